// Round 1
// baseline (4072.673 us; speedup 1.0000x reference)
//
#include <hip/hip_runtime.h>
#include <hip/hip_bf16.h>

#define kB 128
#define kS 1024
#define kT 512
#define kV 1000
#define kE 128
#define kHE 64
#define kHD 66
#define kATT 32
#define kGE 256   // 4*kHE
#define kGD 264   // 4*kHD

typedef __attribute__((ext_vector_type(4))) float f32x4;
typedef __attribute__((ext_vector_type(8))) short bf16x8;
typedef __attribute__((ext_vector_type(8))) unsigned short u16x8;

__device__ __forceinline__ unsigned short f2bf(float f) {
  unsigned int u = __builtin_bit_cast(unsigned int, f);
  u += 0x7FFFu + ((u >> 16) & 1u);   // round-to-nearest-even
  return (unsigned short)(u >> 16);
}
__device__ __forceinline__ float sigf(float x) { return 1.0f / (1.0f + __expf(-x)); }

// exp(tanh(x)): poly (|x|<=0.5, rel err <~1e-4), exact fallback otherwise.
__device__ __forceinline__ float exp_tanh(float x) {
  float u = 1.0f + x*(1.0f + x*(0.5f + x*(-0.16666667f + x*(-0.29166667f + x*(-0.025f)))));
  if (__builtin_expect(fabsf(x) > 0.5f, 0)) u = __expf(tanhf(x));
  return u;
}

// ---------------- prep: embW = emb@Wih^T + b ; W_af = att_fc_W@fin_W ; biases ----
__global__ __launch_bounds__(256) void prep_kernel(
    const float* __restrict__ emb, const float* __restrict__ enc_Wih,
    const float* __restrict__ enc_b, const float* __restrict__ att_fc_W,
    const float* __restrict__ att_fc_b, const float* __restrict__ fin_W,
    const float* __restrict__ fin_b,
    float* __restrict__ embW, float* __restrict__ waf,
    float* __restrict__ abias, float* __restrict__ ainit) {
  int bid = blockIdx.x, tid = threadIdx.x;
  if (bid < kV) {
    float acc = enc_b[tid];
    const float* er = emb + bid * kE;
    const float* wr = enc_Wih + tid * kE;
    for (int e = 0; e < kE; ++e) acc += er[e] * wr[e];
    embW[bid * kGE + tid] = acc;
  } else if (bid < kV + 17) {
    int idx = (bid - kV) * 256 + tid;
    if (idx < kHE * kHD) {
      int k = idx / kHD, m = idx - k * kHD;
      float acc = 0.f;
      for (int e = 0; e < kE; ++e) acc += att_fc_W[k * kE + e] * fin_W[e * kHD + m];
      waf[idx] = acc;
    }
  } else {
    if (tid < kHE) {
      float acc = att_fc_b[tid];
      for (int e = 0; e < kE; ++e) acc += att_fc_W[tid * kE + e] * fin_b[e];
      abias[tid] = acc;
    } else if (tid < 2 * kHE) {
      int k = tid - kHE;
      float acc = att_fc_b[k];
      for (int e = 0; e < kE; ++e) acc += emb[e] * att_fc_W[k * kE + e];
      ainit[k] = acc;
    }
  }
}

// ---------------- fused encoder + decoder: one block per batch element ----------
struct SMem {
  unsigned short enc[kS * kHE];   // 131072 B  bf16, XOR-swizzled rows
  float waf[kHE * 68];            // 17408 B   W_af padded rows
  float gbuf[kGD];                // 1056 B    gates (shared enc/dec)
  float betaW[8 * kATT];          // 1024 B    per-wave beta partials
  float beta[kATT];               // 128 B
  float hdec[68];                 // 272 B     decoder h (66) + zero pad
  float aa[kHE];                  // 256 B     current a-vector
  float hbuf[kHE];                // 256 B     encoder h
  int   toks[kS];                 // 4096 B
};  // total 155,568 B < 160 KiB

__global__ __launch_bounds__(512, 2) void attlstm_main(
    const int* __restrict__ x, const float* __restrict__ embW,
    const float* __restrict__ enc_Whh, const float* __restrict__ att_w_W,
    const float* __restrict__ att_w_b, const float* __restrict__ dec_Wih,
    const float* __restrict__ dec_Whh, const float* __restrict__ dec_b,
    const float* __restrict__ waf_ws, const float* __restrict__ abias_ws,
    const float* __restrict__ ainit_ws, float* __restrict__ out) {
  __shared__ SMem sm;
  const int b = blockIdx.x;
  const int t = threadIdx.x;
  const int lane = t & 63;
  const int wv = t >> 6;

  // ---- setup
  sm.toks[t] = x[b * kS + t];
  sm.toks[t + 512] = x[b * kS + 512 + t];
  if (t < kHE) sm.hbuf[t] = 0.0f;

  // encoder: thread -> gate j = t>>1, half hh = t&1 (k = hh*32 .. +31)
  const int j_enc = t >> 1, hh = t & 1;
  float whhE[32];
  #pragma unroll
  for (int k = 0; k < 32; ++k) whhE[k] = enc_Whh[j_enc * kHE + hh * 32 + k];

  __syncthreads();

  // ---- encoder LSTM over S steps; h written to LDS as swizzled bf16
  float cE = 0.0f;
  float gx = (hh == 0) ? embW[sm.toks[0] * kGE + j_enc] : 0.0f;
  for (int s = 0; s < kS; ++s) {
    int snx = (s + 1 < kS) ? (s + 1) : s;
    float gxn = (hh == 0) ? embW[sm.toks[snx] * kGE + j_enc] : 0.0f;  // prefetch
    const f32x4* h4 = (const f32x4*)sm.hbuf;
    float acc = 0.0f;
    #pragma unroll
    for (int q = 0; q < 8; ++q) {
      f32x4 hv = h4[hh * 8 + q];
      acc += hv.x * whhE[q*4+0] + hv.y * whhE[q*4+1] + hv.z * whhE[q*4+2] + hv.w * whhE[q*4+3];
    }
    acc += __shfl_xor(acc, 1);
    if (hh == 0) sm.gbuf[j_enc] = acc + gx;
    __syncthreads();
    if (t < kHE) {
      float gi = sm.gbuf[t], gf = sm.gbuf[64 + t], gg = sm.gbuf[128 + t], go = sm.gbuf[192 + t];
      cE = sigf(gf) * cE + sigf(gi) * tanhf(gg);
      float h = sigf(go) * tanhf(cE);
      sm.hbuf[t] = h;
      sm.enc[s * kHE + ((((t >> 3) ^ (s & 7)) << 3) | (t & 7))] = f2bf(h);
    }
    __syncthreads();
    gx = gxn;
  }

  // ---- decoder setup
  for (int i = t; i < kHE * kHD; i += 512) {      // W_af -> padded LDS rows
    int k = i / kHD, m = i - k * kHD;
    sm.waf[k * 68 + m] = waf_ws[i];
  }
  if (t < kHE) sm.aa[t] = ainit_ws[t];
  if (t < 68) sm.hdec[t] = 0.0f;

  const int lr = lane & 15;        // s-column within MFMA tile
  const int g = lane >> 4;         // lane group
  float wreg[2][2][8];             // att_w_W elements for A-fragments
  #pragma unroll
  for (int mt = 0; mt < 2; ++mt)
    #pragma unroll
    for (int kc = 0; kc < 2; ++kc)
      #pragma unroll
      for (int jj = 0; jj < 8; ++jj)
        wreg[mt][kc][jj] = att_w_W[(mt * 16 + lr) * kHE + kc * 32 + g * 8 + jj];
  float wbreg[2][4];
  #pragma unroll
  for (int mt = 0; mt < 2; ++mt)
    #pragma unroll
    for (int r = 0; r < 4; ++r) wbreg[mt][r] = att_w_b[mt * 16 + g * 4 + r];

  const int jg = (t < kGD) ? t : (kGD - 1);
  float wih[32], whh[66];
  #pragma unroll
  for (int m = 0; m < 32; ++m) wih[m] = dec_Wih[jg * kATT + m];
  #pragma unroll
  for (int m = 0; m < 66; ++m) whh[m] = dec_Whh[jg * kHD + m];
  float db = dec_b[jg];
  float abias = (t < kHE) ? abias_ws[t] : 0.0f;

  float cD = 0.0f;
  __syncthreads();

  // ---- decoder loop
  const int sbase = wv * 128;
  for (int step = 0; step < kT; ++step) {
    // A-fragments: V[a][k] = att_w_W[a][k] * aa[k]  (bf16)
    const f32x4* aap = (const f32x4*)sm.aa;
    bf16x8 af[2][2];
    #pragma unroll
    for (int kc = 0; kc < 2; ++kc) {
      f32x4 a0 = aap[kc * 8 + g * 2];
      f32x4 a1 = aap[kc * 8 + g * 2 + 1];
      float av[8] = {a0.x, a0.y, a0.z, a0.w, a1.x, a1.y, a1.z, a1.w};
      #pragma unroll
      for (int mt = 0; mt < 2; ++mt) {
        union { bf16x8 v; unsigned short u[8]; } tmp;
        #pragma unroll
        for (int jj = 0; jj < 8; ++jj) tmp.u[jj] = f2bf(wreg[mt][kc][jj] * av[jj]);
        af[mt][kc] = tmp.v;
      }
    }

    float betaAcc[2][4] = {};
    #pragma unroll 2
    for (int nt = 0; nt < 8; ++nt) {
      int s = sbase + nt * 16 + lr;
      int sw = s & 7;
      union { u16x8 u; bf16x8 b; } e0, e1;
      e0.u = *(const u16x8*)&sm.enc[s * kHE + ((g ^ sw) << 3)];
      e1.u = *(const u16x8*)&sm.enc[s * kHE + (((4 + g) ^ sw) << 3)];
      f32x4 z = {0.f, 0.f, 0.f, 0.f};
      f32x4 acc0 = __builtin_amdgcn_mfma_f32_16x16x32_bf16(af[0][0], e0.b, z, 0, 0, 0);
      acc0 = __builtin_amdgcn_mfma_f32_16x16x32_bf16(af[0][1], e1.b, acc0, 0, 0, 0);
      f32x4 acc1 = __builtin_amdgcn_mfma_f32_16x16x32_bf16(af[1][0], e0.b, z, 0, 0, 0);
      acc1 = __builtin_amdgcn_mfma_f32_16x16x32_bf16(af[1][1], e1.b, acc1, 0, 0, 0);
      // lane holds a = mt*16 + g*4 + r for its single s -> softmax denom is local+2 shfl
      float u0[4], u1[4], dsum = 0.f;
      #pragma unroll
      for (int r = 0; r < 4; ++r) {
        u0[r] = exp_tanh(acc0[r] + wbreg[0][r]);
        u1[r] = exp_tanh(acc1[r] + wbreg[1][r]);
        dsum += u0[r] + u1[r];
      }
      dsum += __shfl_xor(dsum, 16);
      dsum += __shfl_xor(dsum, 32);
      float invd = 1.0f / dsum;
      #pragma unroll
      for (int r = 0; r < 4; ++r) {
        betaAcc[0][r] += u0[r] * invd;
        betaAcc[1][r] += u1[r] * invd;
      }
    }
    // reduce beta over the 16 s-lanes, stash per-wave partials
    #pragma unroll
    for (int mt = 0; mt < 2; ++mt)
      #pragma unroll
      for (int r = 0; r < 4; ++r) {
        float v = betaAcc[mt][r];
        v += __shfl_xor(v, 1);
        v += __shfl_xor(v, 2);
        v += __shfl_xor(v, 4);
        v += __shfl_xor(v, 8);
        if (lr == 0) sm.betaW[wv * kATT + mt * 16 + g * 4 + r] = v;
      }
    __syncthreads();
    if (t < kATT) {
      float sum = 0.f;
      #pragma unroll
      for (int w = 0; w < 8; ++w) sum += sm.betaW[w * kATT + t];
      sm.beta[t] = sum;
    }
    __syncthreads();
    // decoder LSTM gates
    if (t < kGD) {
      float gacc = db;
      const f32x4* bp = (const f32x4*)sm.beta;
      #pragma unroll
      for (int q = 0; q < 8; ++q) {
        f32x4 bv = bp[q];
        gacc += bv.x * wih[q*4+0] + bv.y * wih[q*4+1] + bv.z * wih[q*4+2] + bv.w * wih[q*4+3];
      }
      const f32x4* hp = (const f32x4*)sm.hdec;
      #pragma unroll
      for (int q = 0; q < 16; ++q) {
        f32x4 hv = hp[q];
        gacc += hv.x * whh[q*4+0] + hv.y * whh[q*4+1] + hv.z * whh[q*4+2] + hv.w * whh[q*4+3];
      }
      gacc += sm.hdec[64] * whh[64] + sm.hdec[65] * whh[65];
      sm.gbuf[t] = gacc;
    }
    __syncthreads();
    if (t < kHD) {
      float gi = sm.gbuf[t], gf = sm.gbuf[kHD + t], gg = sm.gbuf[2*kHD + t], go = sm.gbuf[3*kHD + t];
      cD = sigf(gf) * cD + sigf(gi) * tanhf(gg);
      float h = sigf(go) * tanhf(cD);
      sm.hdec[t] = h;
      out[(b * kT + step) * kHD + t] = h;
    }
    __syncthreads();
    // a_{t+1} = abias + h @ W_af^T
    if (t < kHE) {
      float v = abias;
      const f32x4* hp = (const f32x4*)sm.hdec;
      const f32x4* wp = (const f32x4*)&sm.waf[t * 68];
      #pragma unroll
      for (int q = 0; q < 16; ++q) {
        f32x4 hv = hp[q]; f32x4 wv4 = wp[q];
        v += hv.x * wv4.x + hv.y * wv4.y + hv.z * wv4.z + hv.w * wv4.w;
      }
      v += sm.hdec[64] * sm.waf[t * 68 + 64] + sm.hdec[65] * sm.waf[t * 68 + 65];
      sm.aa[t] = v;
    }
    __syncthreads();
  }
}

extern "C" void kernel_launch(void* const* d_in, const int* in_sizes, int n_in,
                              void* d_out, int out_size, void* d_ws, size_t ws_size,
                              hipStream_t stream) {
  const int*   x        = (const int*)d_in[0];
  // d_in[1] = c : only its length (T) matters; values unused by the reference
  const float* emb      = (const float*)d_in[2];
  const float* enc_Wih  = (const float*)d_in[3];
  const float* enc_Whh  = (const float*)d_in[4];
  const float* enc_b    = (const float*)d_in[5];
  const float* att_fc_W = (const float*)d_in[6];
  const float* att_fc_b = (const float*)d_in[7];
  const float* att_w_W  = (const float*)d_in[8];
  const float* att_w_b  = (const float*)d_in[9];
  const float* dec_Wih  = (const float*)d_in[10];
  const float* dec_Whh  = (const float*)d_in[11];
  const float* dec_b    = (const float*)d_in[12];
  const float* fin_W    = (const float*)d_in[13];
  const float* fin_b    = (const float*)d_in[14];
  float* out = (float*)d_out;

  float* embW  = (float*)d_ws;           // 1000*256
  float* waf   = embW + kV * kGE;        // 64*66
  float* abias = waf + kHE * kHD;        // 64
  float* ainit = abias + kHE;            // 64

  prep_kernel<<<dim3(kV + 17 + 1), dim3(256), 0, stream>>>(
      emb, enc_Wih, enc_b, att_fc_W, att_fc_b, fin_W, fin_b, embW, waf, abias, ainit);
  attlstm_main<<<dim3(kB), dim3(512), 0, stream>>>(
      x, embW, enc_Whh, att_w_W, att_w_b, dec_Wih, dec_Whh, dec_b,
      waf, abias, ainit, out);
}